// Round 1
// baseline (1021.810 us; speedup 1.0000x reference)
//
#include <hip/hip_runtime.h>
#include <math.h>

#define NTOK 32768
#define DIM  1024
#define NE   7

// ws layout (in 4-byte units). Total = 549920 * 4B = 2.2 MB
#define PN_OFF   0        // 7*1024 normalized prototypes
#define R1_OFF   7168     // 8
#define R2_OFF   7176     // 8
#define R3_OFF   7184     // 8
#define CNT_OFF  7192     // 8 ints
#define PR1_OFF  7200     // 2048*8 block partials (sim pass)
#define PR2_OFF  23584    // 128*8
#define PR3_OFF  24608    // 128*8
#define E0_OFF   25632    // NTOK*8: exp(sim/kappa), slot 7 unused
#define GV_OFF   287776   // NTOK: top-1 gate value
#define LIST_OFF 320544   // NE*NTOK ints: per-expert token lists

#define SEPS   1e-6f
#define LOGEPS 2.220446049250313e-16f

#define SUM7(l) (((((((l)[0] + (l)[1]) + (l)[2]) + (l)[3]) + (l)[4]) + (l)[5]) + (l)[6])

struct ExpPtrs { const float* A[NE]; const float* B[NE]; };

__device__ __forceinline__ float wsum(float v) {
  #pragma unroll
  for (int off = 32; off > 0; off >>= 1) v += __shfl_xor(v, off);
  return v;
}

__device__ __forceinline__ float dot4acc(float4 a, float4 b, float acc) {
  acc = fmaf(a.x, b.x, acc);
  acc = fmaf(a.y, b.y, acc);
  acc = fmaf(a.z, b.z, acc);
  acc = fmaf(a.w, b.w, acc);
  return acc;
}

// ---------------- K0: normalize prototypes, zero counts ----------------
__global__ __launch_bounds__(256) void k_prep(const float* __restrict__ proto,
                                              float* __restrict__ wsf,
                                              int* __restrict__ counts) {
  const int tid = threadIdx.x, w = tid >> 6, lane = tid & 63;
  if (tid < 8) counts[tid] = 0;
  for (int k = w; k < NE; k += 4) {
    float ss = 0.f;
    #pragma unroll
    for (int i = 0; i < 16; ++i) {
      float v = proto[k * DIM + lane + 64 * i];
      ss = fmaf(v, v, ss);
    }
    ss = wsum(ss);
    float inv = 1.f / fmaxf(sqrtf(ss), 1e-12f);
    #pragma unroll
    for (int i = 0; i < 16; ++i)
      wsf[PN_OFF + k * DIM + lane + 64 * i] = proto[k * DIM + lane + 64 * i] * inv;
  }
}

// ---------------- K1: sim -> e0 = exp(sim/kappa), block partials of R1 ----------------
__global__ __launch_bounds__(256) void k_sim(const float* __restrict__ x,
                                             const float* __restrict__ wsf,
                                             float* __restrict__ e0,
                                             float* __restrict__ pr1) {
  const int tid = threadIdx.x, w = tid >> 6, lane = tid & 63;
  const float4* pn4 = (const float4*)(wsf + PN_OFF);
  const int gw = blockIdx.x * 4 + w;   // global wave id, 8192 waves
  float r1a[NE] = {0.f, 0.f, 0.f, 0.f, 0.f, 0.f, 0.f};
  for (int it = 0; it < 4; ++it) {
    const int n = gw + 8192 * it;
    const float4* xr4 = (const float4*)(x + (size_t)n * DIM);
    float xx = 0.f;
    float dk[NE] = {0.f, 0.f, 0.f, 0.f, 0.f, 0.f, 0.f};
    #pragma unroll
    for (int i = 0; i < 4; ++i) {
      float4 xv = xr4[lane + 64 * i];
      xx = dot4acc(xv, xv, xx);
      #pragma unroll
      for (int k = 0; k < NE; ++k)
        dk[k] = dot4acc(xv, pn4[k * 256 + lane + 64 * i], dk[k]);
    }
    xx = wsum(xx);
    #pragma unroll
    for (int k = 0; k < NE; ++k) dk[k] = wsum(dk[k]);
    if (lane == 0) {
      float nrm = fmaxf(sqrtf(xx), 1e-12f);
      #pragma unroll
      for (int k = 0; k < NE; ++k) {
        float ev = expf((dk[k] / nrm) / 0.1f);
        e0[(size_t)n * 8 + k] = ev;
        r1a[k] += ev;
      }
    }
  }
  __shared__ float red[4][8];
  if (lane == 0) {
    #pragma unroll
    for (int k = 0; k < NE; ++k) red[w][k] = r1a[k];
  }
  __syncthreads();
  if (tid == 0) {
    #pragma unroll
    for (int k = 0; k < NE; ++k)
      pr1[blockIdx.x * 8 + k] = ((red[0][k] + red[1][k]) + red[2][k]) + red[3][k];
  }
}

// ---------------- deterministic reduce of block partials ----------------
__global__ __launch_bounds__(256) void k_reduce(const float* __restrict__ src, int nb,
                                                float* __restrict__ dst) {
  __shared__ float red[8][256];
  const int tid = threadIdx.x;
  float a[NE] = {0.f, 0.f, 0.f, 0.f, 0.f, 0.f, 0.f};
  for (int b = tid; b < nb; b += 256) {
    #pragma unroll
    for (int k = 0; k < NE; ++k) a[k] += src[b * 8 + k];
  }
  #pragma unroll
  for (int k = 0; k < NE; ++k) red[k][tid] = a[k];
  __syncthreads();
  for (int off = 128; off > 0; off >>= 1) {
    if (tid < off) {
      #pragma unroll
      for (int k = 0; k < NE; ++k) red[k][tid] += red[k][tid + off];
    }
    __syncthreads();
  }
  if (tid < NE) dst[tid] = red[tid][0];
}

// ---------------- sinkhorn chain passes (DEPTH=1: ->R2 partials, 2: ->R3, 3: route) ----
template<int DEPTH>
__global__ __launch_bounds__(256) void k_pass(const float* __restrict__ e0,
                                              const float* __restrict__ wsf,
                                              float* __restrict__ pr,
                                              int* __restrict__ counts,
                                              int* __restrict__ list,
                                              float* __restrict__ gval) {
  const int tid = threadIdx.x;
  const int n = blockIdx.x * 256 + tid;
  float4 v0 = *(const float4*)(e0 + (size_t)n * 8);
  float4 v1 = *(const float4*)(e0 + (size_t)n * 8 + 4);
  float l[NE] = {v0.x, v0.y, v0.z, v0.w, v1.x, v1.y, v1.z};
  {
    const float* R1 = wsf + R1_OFF;
    #pragma unroll
    for (int k = 0; k < NE; ++k) l[k] = l[k] / (R1[k] + SEPS);
    float C = SUM7(l);
    #pragma unroll
    for (int k = 0; k < NE; ++k) l[k] = l[k] / (C + SEPS);
  }
  if constexpr (DEPTH >= 2) {
    const float* R2 = wsf + R2_OFF;
    #pragma unroll
    for (int k = 0; k < NE; ++k) l[k] = l[k] / (R2[k] + SEPS);
    float C = SUM7(l);
    #pragma unroll
    for (int k = 0; k < NE; ++k) l[k] = l[k] / (C + SEPS);
  }
  if constexpr (DEPTH >= 3) {
    const float* R3 = wsf + R3_OFF;
    #pragma unroll
    for (int k = 0; k < NE; ++k) l[k] = l[k] / (R3[k] + SEPS);
    float C = SUM7(l);
    #pragma unroll
    for (int k = 0; k < NE; ++k) l[k] = l[k] / (C + SEPS);
  }
  if constexpr (DEPTH == 3) {
    // top-1 (first max on ties, matching lax.top_k)
    float best = l[0]; int be = 0;
    #pragma unroll
    for (int k = 1; k < NE; ++k) {
      if (l[k] > best) { best = l[k]; be = k; }
    }
    int pos = atomicAdd(&counts[be], 1);
    list[be * NTOK + pos] = n;
    gval[n] = best;
  } else {
    __shared__ float red[NE][256];
    #pragma unroll
    for (int k = 0; k < NE; ++k) red[k][tid] = l[k];
    __syncthreads();
    for (int off = 128; off > 0; off >>= 1) {
      if (tid < off) {
        #pragma unroll
        for (int k = 0; k < NE; ++k) red[k][tid] += red[k][tid + off];
      }
      __syncthreads();
    }
    if (tid < NE) pr[blockIdx.x * 8 + tid] = red[tid][0];
  }
}

// ---------------- routed expert LoRA: out = log(g * exp(B(A(x)))) ----------------
// Block: 64 tokens, 256 threads (tx = tid&15, ty = tid>>4).
// Phase 1: T[64][D] = X * A^T, K=1024 in KC=32 LDS chunks; thread tile 4m x R (r = tx+16*rr)
// Phase 2: Y[64][1024] = T * B^T in JC=32 column chunks; thread tile 4m x 2j; fused epilogue.
template<int D>
__device__ void expert_gemm(const float* __restrict__ x,
                            const float* __restrict__ Am,
                            const float* __restrict__ Bm,
                            const int* __restrict__ list_e,
                            const float* __restrict__ gval,
                            int cnt, float* __restrict__ out,
                            int* tk, float* gld, float* Ts, float* UN) {
  constexpr int R  = (D + 15) / 16;
  constexpr int SB = D + 4;
  const int m0 = blockIdx.x * 64;
  const int valid = min(64, cnt - m0);
  float* Xs = UN;              // [64][36]
  float* As = UN + 64 * 36;    // [128][36]
  float* Bs = UN;              // [32][SB] (phase 2 overlay)

  const int tid = threadIdx.x;
  const int tx = tid & 15, ty = tid >> 4;

  if (tid < 64) {
    int mm = min(tid, valid - 1);
    int t = list_e[m0 + mm];
    tk[tid] = t;
    gld[tid] = gval[t];
  }
  __syncthreads();

  float acc[4][R];
  #pragma unroll
  for (int i = 0; i < 4; ++i)
    #pragma unroll
    for (int r = 0; r < R; ++r) acc[i][r] = 0.f;

  for (int kc = 0; kc < DIM; kc += 32) {
    if (kc) __syncthreads();
    { // stage X chunk: 64 tokens x 32 k
      int row = tid >> 2, q = tid & 3;
      const float* src = x + (size_t)tk[row] * DIM + kc + q * 8;
      float4 a0 = *(const float4*)src;
      float4 a1 = *(const float4*)(src + 4);
      *(float4*)&Xs[row * 36 + q * 8]     = a0;
      *(float4*)&Xs[row * 36 + q * 8 + 4] = a1;
    }
    // stage A chunk: D x 32
    for (int u = tid; u < 4 * D; u += 256) {
      int r = u >> 2, q = u & 3;
      const float* src = Am + (size_t)r * DIM + kc + q * 8;
      float4 a0 = *(const float4*)src;
      float4 a1 = *(const float4*)(src + 4);
      *(float4*)&As[r * 36 + q * 8]     = a0;
      *(float4*)&As[r * 36 + q * 8 + 4] = a1;
    }
    __syncthreads();
    #pragma unroll
    for (int k4 = 0; k4 < 32; k4 += 4) {
      float4 xv[4];
      #pragma unroll
      for (int i = 0; i < 4; ++i) xv[i] = *(const float4*)&Xs[(ty * 4 + i) * 36 + k4];
      float4 av[R];
      #pragma unroll
      for (int r = 0; r < R; ++r) av[r] = *(const float4*)&As[(tx + 16 * r) * 36 + k4];
      #pragma unroll
      for (int i = 0; i < 4; ++i)
        #pragma unroll
        for (int r = 0; r < R; ++r) acc[i][r] = dot4acc(xv[i], av[r], acc[i][r]);
    }
  }
  __syncthreads();
  #pragma unroll
  for (int i = 0; i < 4; ++i)
    #pragma unroll
    for (int r = 0; r < R; ++r) {
      int rr = tx + 16 * r;
      if (rr < D) Ts[(ty * 4 + i) * 132 + rr] = acc[i][r];
    }
  __syncthreads();

  for (int jc = 0; jc < DIM; jc += 32) {
    if (jc) __syncthreads();
    for (int u = tid; u < 32 * (D / 4); u += 256) {
      int jj = u / (D / 4), f = (u % (D / 4)) * 4;
      *(float4*)&Bs[jj * SB + f] = *(const float4*)(Bm + (size_t)(jc + jj) * D + f);
    }
    __syncthreads();
    float ay[4][2];
    #pragma unroll
    for (int i = 0; i < 4; ++i) { ay[i][0] = 0.f; ay[i][1] = 0.f; }
    #pragma unroll
    for (int r4 = 0; r4 < D; r4 += 4) {
      float4 tv[4];
      #pragma unroll
      for (int i = 0; i < 4; ++i) tv[i] = *(const float4*)&Ts[(ty * 4 + i) * 132 + r4];
      float4 bv[2];
      #pragma unroll
      for (int j = 0; j < 2; ++j) bv[j] = *(const float4*)&Bs[(tx + 16 * j) * SB + r4];
      #pragma unroll
      for (int i = 0; i < 4; ++i)
        #pragma unroll
        for (int j = 0; j < 2; ++j) ay[i][j] = dot4acc(tv[i], bv[j], ay[i][j]);
    }
    #pragma unroll
    for (int i = 0; i < 4; ++i) {
      int m = ty * 4 + i;
      if (m < valid) {
        int t = tk[m];
        float g = gld[m];
        #pragma unroll
        for (int j = 0; j < 2; ++j) {
          int col = jc + tx + 16 * j;
          float c = g * expf(ay[i][j]);
          if (c == 0.f) c = LOGEPS;
          out[(size_t)t * DIM + col] = logf(c);
        }
      }
    }
  }
}

__global__ __launch_bounds__(256) void k_expert(const float* __restrict__ x, ExpPtrs p,
                                                const int* __restrict__ list,
                                                const float* __restrict__ gval,
                                                const int* __restrict__ counts,
                                                float* __restrict__ out) {
  __shared__ int   tk[64];
  __shared__ float gld[64];
  __shared__ float Ts[64 * 132];   // 33792 B
  __shared__ float UN[6912];       // 27648 B: max(Xs+As, Bs)
  const int e = blockIdx.y;
  const int cnt = counts[e];
  if ((int)blockIdx.x * 64 >= cnt) return;
  switch (e) {
    case 0: expert_gemm<8>  (x, p.A[0], p.B[0], list + 0 * NTOK, gval, cnt, out, tk, gld, Ts, UN); break;
    case 1: expert_gemm<16> (x, p.A[1], p.B[1], list + 1 * NTOK, gval, cnt, out, tk, gld, Ts, UN); break;
    case 2: expert_gemm<32> (x, p.A[2], p.B[2], list + 2 * NTOK, gval, cnt, out, tk, gld, Ts, UN); break;
    case 3: expert_gemm<48> (x, p.A[3], p.B[3], list + 3 * NTOK, gval, cnt, out, tk, gld, Ts, UN); break;
    case 4: expert_gemm<64> (x, p.A[4], p.B[4], list + 4 * NTOK, gval, cnt, out, tk, gld, Ts, UN); break;
    case 5: expert_gemm<96> (x, p.A[5], p.B[5], list + 5 * NTOK, gval, cnt, out, tk, gld, Ts, UN); break;
    case 6: expert_gemm<128>(x, p.A[6], p.B[6], list + 6 * NTOK, gval, cnt, out, tk, gld, Ts, UN); break;
  }
}

extern "C" void kernel_launch(void* const* d_in, const int* in_sizes, int n_in,
                              void* d_out, int out_size, void* d_ws, size_t ws_size,
                              hipStream_t stream) {
  const float* x     = (const float*)d_in[0];
  const float* proto = (const float*)d_in[1];
  ExpPtrs p;
  for (int e = 0; e < NE; ++e) {
    p.A[e] = (const float*)d_in[2 + 2 * e];
    p.B[e] = (const float*)d_in[3 + 2 * e];
  }
  float* wsf = (float*)d_ws;
  int*   wsi = (int*)d_ws;
  float* out = (float*)d_out;

  k_prep<<<1, 256, 0, stream>>>(proto, wsf, wsi + CNT_OFF);
  k_sim<<<2048, 256, 0, stream>>>(x, wsf, wsf + E0_OFF, wsf + PR1_OFF);
  k_reduce<<<1, 256, 0, stream>>>(wsf + PR1_OFF, 2048, wsf + R1_OFF);
  k_pass<1><<<128, 256, 0, stream>>>(wsf + E0_OFF, wsf, wsf + PR2_OFF, nullptr, nullptr, nullptr);
  k_reduce<<<1, 256, 0, stream>>>(wsf + PR2_OFF, 128, wsf + R2_OFF);
  k_pass<2><<<128, 256, 0, stream>>>(wsf + E0_OFF, wsf, wsf + PR3_OFF, nullptr, nullptr, nullptr);
  k_reduce<<<1, 256, 0, stream>>>(wsf + PR3_OFF, 128, wsf + R3_OFF);
  k_pass<3><<<128, 256, 0, stream>>>(wsf + E0_OFF, wsf, nullptr, wsi + CNT_OFF, wsi + LIST_OFF, wsf + GV_OFF);
  k_expert<<<dim3(512, NE), 256, 0, stream>>>(x, p, wsi + LIST_OFF, wsf + GV_OFF, wsi + CNT_OFF, out);
}

// Round 2
// 400.173 us; speedup vs baseline: 2.5534x; 2.5534x over previous
//
#include <hip/hip_runtime.h>
#include <math.h>

#define NTOK 32768
#define DIM  1024
#define NE   7

// ws layout (4-byte units). Total ~984096 * 4B = 3.94 MB
#define PN_OFF   0        // 7*1024 normalized prototypes (f32)
#define R1_OFF   7168
#define R2_OFF   7176
#define R3_OFF   7184
#define CNT_OFF  7192     // 8 ints
#define PR1_OFF  7200     // 2048*8
#define PR2_OFF  23584    // 128*8
#define PR3_OFF  24608    // 128*8
#define E0_OFF   25632    // NTOK*8 exp(sim/kappa)
#define LG_OFF   287776   // NTOK: log(top-1 gate)
#define LIST_OFF 320544   // NE*NTOK ints
#define A16_OFF  549920   // bf16 A weights, padded rows (409600 shorts)
#define B16_OFF  754720   // bf16 B weights, padded cols (458752 shorts)

#define SEPS 1e-6f

typedef __attribute__((ext_vector_type(8))) short short8v;
typedef __attribute__((ext_vector_type(4))) float f32x4;

// per-expert geometry: D = lora dim, DP = K-padded (mult 32), DAP = N-padded (mult 16)
constexpr int DV[7]   = {8, 16, 32, 48, 64, 96, 128};
constexpr int DPV[7]  = {32, 32, 32, 64, 64, 96, 128};
constexpr int DAPV[7] = {16, 16, 32, 48, 64, 96, 128};
constexpr int AOV[7]  = {0, 16384, 32768, 65536, 114688, 180224, 278528};  // dap*1024 prefix
constexpr int BOV[7]  = {0, 32768, 65536, 98304, 163840, 229376, 327680}; // dp*1024 prefix

struct ExpPtrs { const float* A[NE]; const float* B[NE]; };

__device__ __forceinline__ short f2bf(float f) {
  union { float f; unsigned u; } v; v.f = f;
  return (short)((v.u + 0x7FFFu + ((v.u >> 16) & 1u)) >> 16);  // RNE
}

__device__ __forceinline__ float wsum(float v) {
  #pragma unroll
  for (int off = 32; off > 0; off >>= 1) v += __shfl_xor(v, off);
  return v;
}

__device__ __forceinline__ float dot4acc(float4 a, float4 b, float acc) {
  acc = fmaf(a.x, b.x, acc);
  acc = fmaf(a.y, b.y, acc);
  acc = fmaf(a.z, b.z, acc);
  acc = fmaf(a.w, b.w, acc);
  return acc;
}

__device__ __forceinline__ void ecfg(int e, int& d, int& dp, int& dap, int& ao, int& bo) {
  switch (e) {
    case 0: d = 8;   dp = 32;  dap = 16;  ao = 0;      bo = 0;      break;
    case 1: d = 16;  dp = 32;  dap = 16;  ao = 16384;  bo = 32768;  break;
    case 2: d = 32;  dp = 32;  dap = 32;  ao = 32768;  bo = 65536;  break;
    case 3: d = 48;  dp = 64;  dap = 48;  ao = 65536;  bo = 98304;  break;
    case 4: d = 64;  dp = 64;  dap = 64;  ao = 114688; bo = 163840; break;
    case 5: d = 96;  dp = 96;  dap = 96;  ao = 180224; bo = 229376; break;
    default: d = 128; dp = 128; dap = 128; ao = 278528; bo = 327680; break;
  }
}

// ---------------- K0: normalize prototypes, zero counts ----------------
__global__ __launch_bounds__(256) void k_prep(const float* __restrict__ proto,
                                              float* __restrict__ wsf,
                                              int* __restrict__ counts) {
  const int tid = threadIdx.x, w = tid >> 6, lane = tid & 63;
  if (tid < 8) counts[tid] = 0;
  for (int k = w; k < NE; k += 4) {
    float ss = 0.f;
    #pragma unroll
    for (int i = 0; i < 16; ++i) {
      float v = proto[k * DIM + lane + 64 * i];
      ss = fmaf(v, v, ss);
    }
    ss = wsum(ss);
    float inv = 1.f / fmaxf(sqrtf(ss), 1e-12f);
    #pragma unroll
    for (int i = 0; i < 16; ++i)
      wsf[PN_OFF + k * DIM + lane + 64 * i] = proto[k * DIM + lane + 64 * i] * inv;
  }
}

// ---------------- K0b: convert A/B weights to bf16 (padded) ----------------
__global__ __launch_bounds__(256) void k_conv(ExpPtrs p, short* __restrict__ A16,
                                              short* __restrict__ B16) {
  const int e = blockIdx.y;
  int d, dp, dap, ao, bo;
  ecfg(e, d, dp, dap, ao, bo);
  const float* A = p.A[e];
  const float* B = p.B[e];
  short* Ad = A16 + ao;
  short* Bd = B16 + bo;
  const int t0 = blockIdx.x * 256 + threadIdx.x;
  for (int i = t0; i < dap * DIM; i += 16 * 256) {
    int row = i >> 10;
    Ad[i] = (row < d) ? f2bf(A[i]) : (short)0;
  }
  for (int i = t0; i < DIM * dp; i += 16 * 256) {
    int j = i / dp, r = i - j * dp;
    Bd[i] = (r < d) ? f2bf(B[j * d + r]) : (short)0;
  }
}

// ---------------- K1: sim -> e0 = exp(sim/kappa), block partials of R1 ----------------
__global__ __launch_bounds__(256) void k_sim(const float* __restrict__ x,
                                             const float* __restrict__ wsf,
                                             float* __restrict__ e0,
                                             float* __restrict__ pr1) {
  const int tid = threadIdx.x, w = tid >> 6, lane = tid & 63;
  const float4* pn4 = (const float4*)(wsf + PN_OFF);
  const int gw = blockIdx.x * 4 + w;
  float r1a[NE] = {0.f, 0.f, 0.f, 0.f, 0.f, 0.f, 0.f};
  for (int it = 0; it < 4; ++it) {
    const int n = gw + 8192 * it;
    const float4* xr4 = (const float4*)(x + (size_t)n * DIM);
    float xx = 0.f;
    float dk[NE] = {0.f, 0.f, 0.f, 0.f, 0.f, 0.f, 0.f};
    #pragma unroll
    for (int i = 0; i < 4; ++i) {
      float4 xv = xr4[lane + 64 * i];
      xx = dot4acc(xv, xv, xx);
      #pragma unroll
      for (int k = 0; k < NE; ++k)
        dk[k] = dot4acc(xv, pn4[k * 256 + lane + 64 * i], dk[k]);
    }
    xx = wsum(xx);
    #pragma unroll
    for (int k = 0; k < NE; ++k) dk[k] = wsum(dk[k]);
    if (lane == 0) {
      float nrm = fmaxf(sqrtf(xx), 1e-12f);
      #pragma unroll
      for (int k = 0; k < NE; ++k) {
        float ev = expf((dk[k] / nrm) / 0.1f);
        e0[(size_t)n * 8 + k] = ev;
        r1a[k] += ev;
      }
    }
  }
  __shared__ float red[4][8];
  if (lane == 0) {
    #pragma unroll
    for (int k = 0; k < NE; ++k) red[w][k] = r1a[k];
  }
  __syncthreads();
  if (tid == 0) {
    #pragma unroll
    for (int k = 0; k < NE; ++k)
      pr1[blockIdx.x * 8 + k] = ((red[0][k] + red[1][k]) + red[2][k]) + red[3][k];
  }
}

// ---------------- deterministic reduce of block partials ----------------
__global__ __launch_bounds__(256) void k_reduce(const float* __restrict__ src, int nb,
                                                float* __restrict__ dst) {
  __shared__ float red[8][256];
  const int tid = threadIdx.x;
  float a[NE] = {0.f, 0.f, 0.f, 0.f, 0.f, 0.f, 0.f};
  for (int b = tid; b < nb; b += 256) {
    #pragma unroll
    for (int k = 0; k < NE; ++k) a[k] += src[b * 8 + k];
  }
  #pragma unroll
  for (int k = 0; k < NE; ++k) red[k][tid] = a[k];
  __syncthreads();
  for (int off = 128; off > 0; off >>= 1) {
    if (tid < off) {
      #pragma unroll
      for (int k = 0; k < NE; ++k) red[k][tid] += red[k][tid + off];
    }
    __syncthreads();
  }
  if (tid < NE) dst[tid] = red[tid][0];
}

#define SUM7(l) (((((((l)[0] + (l)[1]) + (l)[2]) + (l)[3]) + (l)[4]) + (l)[5]) + (l)[6])

// ---------------- sinkhorn chain passes ----------------
template<int DEPTH>
__global__ __launch_bounds__(256) void k_pass(const float* __restrict__ e0,
                                              const float* __restrict__ wsf,
                                              float* __restrict__ pr,
                                              int* __restrict__ counts,
                                              int* __restrict__ list,
                                              float* __restrict__ lgv) {
  const int tid = threadIdx.x;
  const int n = blockIdx.x * 256 + tid;
  float4 v0 = *(const float4*)(e0 + (size_t)n * 8);
  float4 v1 = *(const float4*)(e0 + (size_t)n * 8 + 4);
  float l[NE] = {v0.x, v0.y, v0.z, v0.w, v1.x, v1.y, v1.z};
  {
    const float* R1 = wsf + R1_OFF;
    #pragma unroll
    for (int k = 0; k < NE; ++k) l[k] = l[k] / (R1[k] + SEPS);
    float C = SUM7(l);
    #pragma unroll
    for (int k = 0; k < NE; ++k) l[k] = l[k] / (C + SEPS);
  }
  if constexpr (DEPTH >= 2) {
    const float* R2 = wsf + R2_OFF;
    #pragma unroll
    for (int k = 0; k < NE; ++k) l[k] = l[k] / (R2[k] + SEPS);
    float C = SUM7(l);
    #pragma unroll
    for (int k = 0; k < NE; ++k) l[k] = l[k] / (C + SEPS);
  }
  if constexpr (DEPTH >= 3) {
    const float* R3 = wsf + R3_OFF;
    #pragma unroll
    for (int k = 0; k < NE; ++k) l[k] = l[k] / (R3[k] + SEPS);
    float C = SUM7(l);
    #pragma unroll
    for (int k = 0; k < NE; ++k) l[k] = l[k] / (C + SEPS);
  }
  if constexpr (DEPTH == 3) {
    float best = l[0]; int be = 0;
    #pragma unroll
    for (int k = 1; k < NE; ++k) {
      if (l[k] > best) { best = l[k]; be = k; }
    }
    int pos = atomicAdd(&counts[be], 1);
    list[be * NTOK + pos] = n;
    lgv[n] = logf(best);
  } else {
    __shared__ float red[NE][256];
    #pragma unroll
    for (int k = 0; k < NE; ++k) red[k][tid] = l[k];
    __syncthreads();
    for (int off = 128; off > 0; off >>= 1) {
      if (tid < off) {
        #pragma unroll
        for (int k = 0; k < NE; ++k) red[k][tid] += red[k][tid + off];
      }
      __syncthreads();
    }
    if (tid < NE) pr[blockIdx.x * 8 + tid] = red[tid][0];
  }
}

// ---------------- routed expert LoRA via bf16 MFMA ----------------
// Block = 64 tokens, 4 waves; wave w owns tokens [m0 + w*16, +16). No __syncthreads.
// Phase 1: T[16][D] = X16 * A^T  (K=1024, mfma 16x16x32, acc over 32 k-steps)
// Phase 2: Y[16][1024] = T * B^T (K=DP), epilogue out = log(g) + y.
template<int E>
__device__ void expert_mfma(const float* __restrict__ x,
                            const short* __restrict__ A16,
                            const short* __restrict__ B16,
                            const int* __restrict__ list_e,
                            const float* __restrict__ lg,
                            int cnt, float* __restrict__ out,
                            short* Ts) {
  constexpr int D = DV[E], DP = DPV[E], DAP = DAPV[E];
  constexpr int NT1 = DAP / 16;   // phase-1 N-tiles
  constexpr int KS2 = DP / 32;    // phase-2 K-steps
  constexpr int SP  = DP + 8;     // LDS row pitch (bf16) — breaks bank conflicts
  (void)D;
  const short* Am = A16 + AOV[E];
  const short* Bp = B16 + BOV[E];
  const int tid = threadIdx.x;
  const int w = tid >> 6, lane = tid & 63;
  const int lo = lane & 15, hi = lane >> 4;
  const int m0 = blockIdx.x * 64 + w * 16;

  short* Tw = Ts + w * 16 * SP;

  // zero T cols [DAP, DP) (read by phase 2, not written by phase 1)
  if constexpr (DAP < DP) {
    constexpr int W = DP - DAP;
    for (int i = lane; i < 16 * W; i += 64) {
      int r = i / W, c = i - r * W;
      Tw[r * SP + DAP + c] = 0;
    }
  }

  // ---- phase 1 ----
  const int myTok = list_e[min(m0 + lo, cnt - 1)];
  const float* xp = x + (size_t)myTok * DIM + hi * 8;
  const short* ApL = Am + lo * DIM + hi * 8;

  f32x4 acc1[NT1];
  #pragma unroll
  for (int t = 0; t < NT1; ++t) acc1[t] = (f32x4){0.f, 0.f, 0.f, 0.f};

  float4 nx0 = *(const float4*)(xp);
  float4 nx1 = *(const float4*)(xp + 4);
  #pragma unroll 2
  for (int kc = 0; kc < DIM; kc += 32) {
    float4 x0 = nx0, x1 = nx1;
    if (kc + 32 < DIM) {
      nx0 = *(const float4*)(xp + kc + 32);
      nx1 = *(const float4*)(xp + kc + 36);
    }
    short8v af;
    af[0] = f2bf(x0.x); af[1] = f2bf(x0.y); af[2] = f2bf(x0.z); af[3] = f2bf(x0.w);
    af[4] = f2bf(x1.x); af[5] = f2bf(x1.y); af[6] = f2bf(x1.z); af[7] = f2bf(x1.w);
    #pragma unroll
    for (int t = 0; t < NT1; ++t) {
      short8v bf = *(const short8v*)(ApL + t * 16 * DIM + kc);
      acc1[t] = __builtin_amdgcn_mfma_f32_16x16x32_bf16(af, bf, acc1[t], 0, 0, 0);
    }
  }

  // write T (C/D layout: row = hi*4+j, col = t*16+lo)
  #pragma unroll
  for (int t = 0; t < NT1; ++t)
    #pragma unroll
    for (int j = 0; j < 4; ++j)
      Tw[(hi * 4 + j) * SP + t * 16 + lo] = f2bf(acc1[t][j]);

  // ---- phase 2 ----
  short8v tf[KS2];
  #pragma unroll
  for (int ks = 0; ks < KS2; ++ks)
    tf[ks] = *(const short8v*)(Tw + lo * SP + ks * 32 + hi * 8);

  float  lgvr[4];
  float* op[4];
  #pragma unroll
  for (int j = 0; j < 4; ++j) {
    int t = list_e[min(m0 + hi * 4 + j, cnt - 1)];
    lgvr[j] = lg[t];
    op[j] = out + (size_t)t * DIM + lo;
  }

  const short* BpL = Bp + lo * DP + hi * 8;
  #pragma unroll 4
  for (int nt = 0; nt < 64; ++nt) {
    f32x4 acc = (f32x4){0.f, 0.f, 0.f, 0.f};
    #pragma unroll
    for (int ks = 0; ks < KS2; ++ks) {
      short8v bf = *(const short8v*)(BpL + (size_t)nt * 16 * DP + ks * 32);
      acc = __builtin_amdgcn_mfma_f32_16x16x32_bf16(tf[ks], bf, acc, 0, 0, 0);
    }
    #pragma unroll
    for (int j = 0; j < 4; ++j)
      op[j][nt * 16] = acc[j] + lgvr[j];
  }
}

__global__ __launch_bounds__(256) void k_expert(const float* __restrict__ x,
                                                const short* __restrict__ A16,
                                                const short* __restrict__ B16,
                                                const int* __restrict__ list,
                                                const float* __restrict__ lg,
                                                const int* __restrict__ counts,
                                                float* __restrict__ out) {
  __shared__ __align__(16) short Ts[4 * 16 * 136];  // 17408 B
  const int e = blockIdx.y;
  const int cnt = counts[e];
  if ((int)blockIdx.x * 64 >= cnt) return;
  switch (e) {
    case 0: expert_mfma<0>(x, A16, B16, list + 0 * NTOK, lg, cnt, out, Ts); break;
    case 1: expert_mfma<1>(x, A16, B16, list + 1 * NTOK, lg, cnt, out, Ts); break;
    case 2: expert_mfma<2>(x, A16, B16, list + 2 * NTOK, lg, cnt, out, Ts); break;
    case 3: expert_mfma<3>(x, A16, B16, list + 3 * NTOK, lg, cnt, out, Ts); break;
    case 4: expert_mfma<4>(x, A16, B16, list + 4 * NTOK, lg, cnt, out, Ts); break;
    case 5: expert_mfma<5>(x, A16, B16, list + 5 * NTOK, lg, cnt, out, Ts); break;
    case 6: expert_mfma<6>(x, A16, B16, list + 6 * NTOK, lg, cnt, out, Ts); break;
  }
}

extern "C" void kernel_launch(void* const* d_in, const int* in_sizes, int n_in,
                              void* d_out, int out_size, void* d_ws, size_t ws_size,
                              hipStream_t stream) {
  const float* x     = (const float*)d_in[0];
  const float* proto = (const float*)d_in[1];
  ExpPtrs p;
  for (int e = 0; e < NE; ++e) {
    p.A[e] = (const float*)d_in[2 + 2 * e];
    p.B[e] = (const float*)d_in[3 + 2 * e];
  }
  float* wsf = (float*)d_ws;
  int*   wsi = (int*)d_ws;
  short* A16 = (short*)(wsf + A16_OFF);
  short* B16 = (short*)(wsf + B16_OFF);
  float* out = (float*)d_out;

  k_prep<<<1, 256, 0, stream>>>(proto, wsf, wsi + CNT_OFF);
  k_conv<<<dim3(16, NE), 256, 0, stream>>>(p, A16, B16);
  k_sim<<<2048, 256, 0, stream>>>(x, wsf, wsf + E0_OFF, wsf + PR1_OFF);
  k_reduce<<<1, 256, 0, stream>>>(wsf + PR1_OFF, 2048, wsf + R1_OFF);
  k_pass<1><<<128, 256, 0, stream>>>(wsf + E0_OFF, wsf, wsf + PR2_OFF, nullptr, nullptr, nullptr);
  k_reduce<<<1, 256, 0, stream>>>(wsf + PR2_OFF, 128, wsf + R2_OFF);
  k_pass<2><<<128, 256, 0, stream>>>(wsf + E0_OFF, wsf, wsf + PR3_OFF, nullptr, nullptr, nullptr);
  k_reduce<<<1, 256, 0, stream>>>(wsf + PR3_OFF, 128, wsf + R3_OFF);
  k_pass<3><<<128, 256, 0, stream>>>(wsf + E0_OFF, wsf, nullptr, wsi + CNT_OFF, wsi + LIST_OFF, wsf + LG_OFF);
  k_expert<<<dim3(512, NE), 256, 0, stream>>>(x, A16, B16, wsi + LIST_OFF, wsf + LG_OFF, wsi + CNT_OFF, out);
}

// Round 3
// 324.792 us; speedup vs baseline: 3.1460x; 1.2321x over previous
//
#include <hip/hip_runtime.h>
#include <math.h>

#define NTOK 32768
#define DIM  1024
#define NE   7

// ws layout (4-byte units), ~3.94 MB
#define PN_OFF   0        // 7*1024 normalized prototypes (f32)
#define R1_OFF   7168
#define R2_OFF   7176
#define R3_OFF   7184
#define CNT_OFF  7192     // 8 ints
#define PR1_OFF  7200     // 2048*8
#define PR2_OFF  23584    // 128*8
#define PR3_OFF  24608    // 128*8
#define E0_OFF   25632    // NTOK*8 exp(sim/kappa)
#define LG_OFF   287776   // NTOK: log(top-1 gate)
#define LIST_OFF 320544   // NE*NTOK ints
#define A16_OFF  549920   // bf16 A weights (padded rows)
#define B16_OFF  754720   // bf16 B weights (padded cols)

#define SEPS 1e-6f

typedef __attribute__((ext_vector_type(8))) short short8v;
typedef __attribute__((ext_vector_type(4))) float f32x4;

// per-expert geometry
constexpr int DV[7]   = {8, 16, 32, 48, 64, 96, 128};
constexpr int DPV[7]  = {32, 32, 32, 64, 64, 96, 128};   // K-padded (mult 32)
constexpr int DAPV[7] = {16, 16, 32, 48, 64, 96, 128};   // N-padded (mult 16)
constexpr int AOV[7]  = {0, 16384, 32768, 65536, 114688, 180224, 278528};
constexpr int BOV[7]  = {0, 32768, 65536, 98304, 163840, 229376, 327680};

struct ExpPtrs { const float* A[NE]; const float* B[NE]; };

__device__ __forceinline__ short f2bf(float f) {
  union { float f; unsigned u; } v; v.f = f;
  return (short)((v.u + 0x7FFFu + ((v.u >> 16) & 1u)) >> 16);  // RNE
}

__device__ __forceinline__ float wsum(float v) {
  #pragma unroll
  for (int off = 32; off > 0; off >>= 1) v += __shfl_xor(v, off);
  return v;
}

__device__ __forceinline__ float dot4acc(float4 a, float4 b, float acc) {
  acc = fmaf(a.x, b.x, acc);
  acc = fmaf(a.y, b.y, acc);
  acc = fmaf(a.z, b.z, acc);
  acc = fmaf(a.w, b.w, acc);
  return acc;
}

__device__ __forceinline__ void ecfg(int e, int& d, int& dp, int& dap, int& ao, int& bo) {
  switch (e) {
    case 0: d = 8;   dp = 32;  dap = 16;  ao = 0;      bo = 0;      break;
    case 1: d = 16;  dp = 32;  dap = 16;  ao = 16384;  bo = 32768;  break;
    case 2: d = 32;  dp = 32;  dap = 32;  ao = 32768;  bo = 65536;  break;
    case 3: d = 48;  dp = 64;  dap = 48;  ao = 65536;  bo = 98304;  break;
    case 4: d = 64;  dp = 64;  dap = 64;  ao = 114688; bo = 163840; break;
    case 5: d = 96;  dp = 96;  dap = 96;  ao = 180224; bo = 229376; break;
    default: d = 128; dp = 128; dap = 128; ao = 278528; bo = 327680; break;
  }
}

// ---------------- K0: bf16 weight conversion + (block x==0) proto prep ----------------
__global__ __launch_bounds__(256) void k_conv(ExpPtrs p, short* __restrict__ A16,
                                              short* __restrict__ B16,
                                              const float* __restrict__ proto,
                                              float* __restrict__ wsf,
                                              int* __restrict__ counts) {
  const int e = blockIdx.y;
  const int tid = threadIdx.x;
  int d, dp, dap, ao, bo;
  ecfg(e, d, dp, dap, ao, bo);

  if (blockIdx.x == 0) {
    // normalize prototype row e; zero counts (e==0)
    __shared__ float pred[4];
    if (e == 0 && tid < 8) counts[tid] = 0;
    const int w = tid >> 6, lane = tid & 63;
    float v4[4], ss = 0.f;
    #pragma unroll
    for (int i = 0; i < 4; ++i) {
      v4[i] = proto[e * DIM + tid + 256 * i];
      ss = fmaf(v4[i], v4[i], ss);
    }
    ss = wsum(ss);
    if (lane == 0) pred[w] = ss;
    __syncthreads();
    float tot = ((pred[0] + pred[1]) + pred[2]) + pred[3];
    float inv = 1.f / fmaxf(sqrtf(tot), 1e-12f);
    #pragma unroll
    for (int i = 0; i < 4; ++i)
      wsf[PN_OFF + e * DIM + tid + 256 * i] = v4[i] * inv;
  }

  const float* A = p.A[e];
  const float* B = p.B[e];
  short* Ad = A16 + ao;
  short* Bd = B16 + bo;
  const int t0 = blockIdx.x * 256 + tid;
  for (int i = t0; i < dap * DIM; i += 16 * 256) {
    int row = i >> 10;
    Ad[i] = (row < d) ? f2bf(A[i]) : (short)0;
  }
  for (int i = t0; i < DIM * dp; i += 16 * 256) {
    int j = i / dp, r = i - j * dp;
    Bd[i] = (r < d) ? f2bf(B[j * d + r]) : (short)0;
  }
}

// ---------------- K1: sim -> e0 = exp(sim/kappa), block partials of R1 ----------------
__global__ __launch_bounds__(256) void k_sim(const float* __restrict__ x,
                                             const float* __restrict__ wsf,
                                             float* __restrict__ e0,
                                             float* __restrict__ pr1) {
  const int tid = threadIdx.x, w = tid >> 6, lane = tid & 63;
  const float4* pn4 = (const float4*)(wsf + PN_OFF);
  const int gw = blockIdx.x * 4 + w;
  float r1a[NE] = {0.f, 0.f, 0.f, 0.f, 0.f, 0.f, 0.f};
  for (int it = 0; it < 4; ++it) {
    const int n = gw + 8192 * it;
    const float4* xr4 = (const float4*)(x + (size_t)n * DIM);
    float xx = 0.f;
    float dk[NE] = {0.f, 0.f, 0.f, 0.f, 0.f, 0.f, 0.f};
    #pragma unroll
    for (int i = 0; i < 4; ++i) {
      float4 xv = xr4[lane + 64 * i];
      xx = dot4acc(xv, xv, xx);
      #pragma unroll
      for (int k = 0; k < NE; ++k)
        dk[k] = dot4acc(xv, pn4[k * 256 + lane + 64 * i], dk[k]);
    }
    xx = wsum(xx);
    #pragma unroll
    for (int k = 0; k < NE; ++k) dk[k] = wsum(dk[k]);
    if (lane == 0) {
      float nrm = fmaxf(sqrtf(xx), 1e-12f);
      #pragma unroll
      for (int k = 0; k < NE; ++k) {
        float ev = expf((dk[k] / nrm) / 0.1f);
        e0[(size_t)n * 8 + k] = ev;
        r1a[k] += ev;
      }
    }
  }
  __shared__ float red[4][8];
  if (lane == 0) {
    #pragma unroll
    for (int k = 0; k < NE; ++k) red[w][k] = r1a[k];
  }
  __syncthreads();
  if (tid == 0) {
    #pragma unroll
    for (int k = 0; k < NE; ++k)
      pr1[blockIdx.x * 8 + k] = ((red[0][k] + red[1][k]) + red[2][k]) + red[3][k];
  }
}

#define SUM7(l) (((((((l)[0] + (l)[1]) + (l)[2]) + (l)[3]) + (l)[4]) + (l)[5]) + (l)[6])

// ---------------- sinkhorn passes; each self-reduces prior partials ----------------
// DEPTH=1: reduce PR1->R1(store), chain d1, write PR2 partials
// DEPTH=2: reduce PR2->R2(store), chain d2 (R1 from ws), write PR3
// DEPTH=3: reduce PR3->R3, chain d3 (R1,R2 from ws), route (top-1)
template<int DEPTH>
__global__ __launch_bounds__(256) void k_pass(const float* __restrict__ e0,
                                              float* __restrict__ wsf,
                                              const float* __restrict__ src, int nb,
                                              float* __restrict__ prOut,
                                              int* __restrict__ counts,
                                              int* __restrict__ list,
                                              float* __restrict__ lgv) {
  __shared__ float red2[8][33];
  __shared__ float Rcur[8];
  const int tid = threadIdx.x;
  {
    const int k = tid & 7, m = tid >> 3;
    float a = 0.f;
    for (int b = m; b < nb; b += 32) a += src[b * 8 + k];
    red2[k][m] = a;
    __syncthreads();
    if (tid < 8) {
      float s = 0.f;
      for (int mm = 0; mm < 32; ++mm) s += red2[tid][mm];
      Rcur[tid] = s;
      if (blockIdx.x == 0) {
        int roff = (DEPTH == 1) ? R1_OFF : (DEPTH == 2) ? R2_OFF : R3_OFF;
        wsf[roff + tid] = s;
      }
    }
    __syncthreads();
  }

  const int n = blockIdx.x * 256 + tid;
  float4 v0 = *(const float4*)(e0 + (size_t)n * 8);
  float4 v1 = *(const float4*)(e0 + (size_t)n * 8 + 4);
  float l[NE] = {v0.x, v0.y, v0.z, v0.w, v1.x, v1.y, v1.z};
  {
    const float* R1 = (DEPTH == 1) ? Rcur : (wsf + R1_OFF);
    #pragma unroll
    for (int k = 0; k < NE; ++k) l[k] = l[k] / (R1[k] + SEPS);
    float C = SUM7(l);
    #pragma unroll
    for (int k = 0; k < NE; ++k) l[k] = l[k] / (C + SEPS);
  }
  if constexpr (DEPTH >= 2) {
    const float* R2 = (DEPTH == 2) ? Rcur : (wsf + R2_OFF);
    #pragma unroll
    for (int k = 0; k < NE; ++k) l[k] = l[k] / (R2[k] + SEPS);
    float C = SUM7(l);
    #pragma unroll
    for (int k = 0; k < NE; ++k) l[k] = l[k] / (C + SEPS);
  }
  if constexpr (DEPTH >= 3) {
    const float* R3 = Rcur;
    #pragma unroll
    for (int k = 0; k < NE; ++k) l[k] = l[k] / (R3[k] + SEPS);
    float C = SUM7(l);
    #pragma unroll
    for (int k = 0; k < NE; ++k) l[k] = l[k] / (C + SEPS);
  }
  if constexpr (DEPTH == 3) {
    float best = l[0]; int be = 0;
    #pragma unroll
    for (int k = 1; k < NE; ++k) {
      if (l[k] > best) { best = l[k]; be = k; }
    }
    int pos = atomicAdd(&counts[be], 1);
    list[be * NTOK + pos] = n;
    lgv[n] = logf(best);
  } else {
    __shared__ float red[NE][256];
    #pragma unroll
    for (int k = 0; k < NE; ++k) red[k][tid] = l[k];
    __syncthreads();
    for (int off = 128; off > 0; off >>= 1) {
      if (tid < off) {
        #pragma unroll
        for (int k = 0; k < NE; ++k) red[k][tid] += red[k][tid + off];
      }
      __syncthreads();
    }
    if (tid < NE) prOut[blockIdx.x * 8 + tid] = red[tid][0];
  }
}

// ---------------- routed expert LoRA via bf16 MFMA, K-split + col-split ----------------
// Block = 16 tokens, 4 waves.
// Phase 1: wave w computes partial T over K-chunk [w*256, w*256+256); LDS 2-region
//          reduce (w0/w1 write, w2/w3 add, all waves combine -> bf16 T in LDS).
// Phase 2: wave w computes output cols [w*256, w*256+256) = 16 N-tiles; out = y + log(g).
template<int E>
__device__ void expert_mfma(const float* __restrict__ x,
                            const short* __restrict__ A16,
                            const short* __restrict__ B16,
                            const int* __restrict__ list_e,
                            const float* __restrict__ lg,
                            int cnt, float* __restrict__ out,
                            char* lds) {
  constexpr int DP = DPV[E], DAP = DAPV[E];
  constexpr int NT1 = DAP / 16;   // phase-1 N-tiles
  constexpr int KS2 = DP / 32;    // phase-2 K-steps
  constexpr int PP  = DAP + 4;    // f32 partial pitch
  constexpr int SP  = DP + 8;     // bf16 T pitch
  float* P = (float*)lds;                         // [2][16][PP]
  short* T = (short*)(lds + 2 * 16 * PP * 4);     // [16][SP]

  const short* Am = A16 + AOV[E];
  const short* Bp = B16 + BOV[E];
  const int tid = threadIdx.x;
  const int w = tid >> 6, lane = tid & 63;
  const int lo = lane & 15, hi = lane >> 4;
  const int m0 = blockIdx.x * 16;

  // ---- phase 1: partial over K-chunk of 256 ----
  const int myTok = list_e[min(m0 + lo, cnt - 1)];
  const float* xp = x + (size_t)myTok * DIM + w * 256 + hi * 8;
  const short* ApL = Am + lo * DIM + w * 256 + hi * 8;

  f32x4 acc1[NT1];
  #pragma unroll
  for (int t = 0; t < NT1; ++t) acc1[t] = (f32x4){0.f, 0.f, 0.f, 0.f};

  float4 nx0 = *(const float4*)(xp);
  float4 nx1 = *(const float4*)(xp + 4);
  #pragma unroll
  for (int kc = 0; kc < 256; kc += 32) {
    float4 x0 = nx0, x1 = nx1;
    if (kc + 32 < 256) {
      nx0 = *(const float4*)(xp + kc + 32);
      nx1 = *(const float4*)(xp + kc + 36);
    }
    short8v af;
    af[0] = f2bf(x0.x); af[1] = f2bf(x0.y); af[2] = f2bf(x0.z); af[3] = f2bf(x0.w);
    af[4] = f2bf(x1.x); af[5] = f2bf(x1.y); af[6] = f2bf(x1.z); af[7] = f2bf(x1.w);
    #pragma unroll
    for (int t = 0; t < NT1; ++t) {
      short8v bf = *(const short8v*)(ApL + t * 16 * DIM + kc);
      acc1[t] = __builtin_amdgcn_mfma_f32_16x16x32_bf16(af, bf, acc1[t], 0, 0, 0);
    }
  }

  // ---- LDS reduce: waves 0,1 write; waves 2,3 add; combine -> bf16 T ----
  float* Pw = P + (w & 1) * 16 * PP;
  if (w < 2) {
    #pragma unroll
    for (int t = 0; t < NT1; ++t)
      #pragma unroll
      for (int j = 0; j < 4; ++j)
        Pw[(hi * 4 + j) * PP + t * 16 + lo] = acc1[t][j];
  }
  __syncthreads();
  if (w >= 2) {
    #pragma unroll
    for (int t = 0; t < NT1; ++t)
      #pragma unroll
      for (int j = 0; j < 4; ++j)
        Pw[(hi * 4 + j) * PP + t * 16 + lo] += acc1[t][j];
  }
  __syncthreads();
  for (int i = tid; i < 16 * DP; i += 256) {
    int r = i / DP, c = i - r * DP;
    float v = (c < DAP) ? (P[r * PP + c] + P[(16 + r) * PP + c]) : 0.f;
    T[r * SP + c] = f2bf(v);
  }
  __syncthreads();

  // ---- phase 2: cols [w*256, +256) ----
  short8v tf[KS2];
  #pragma unroll
  for (int ks = 0; ks < KS2; ++ks)
    tf[ks] = *(const short8v*)(T + lo * SP + ks * 32 + hi * 8);

  float  lgvr[4];
  float* op[4];
  #pragma unroll
  for (int j = 0; j < 4; ++j) {
    int t = list_e[min(m0 + hi * 4 + j, cnt - 1)];
    lgvr[j] = lg[t];
    op[j] = out + (size_t)t * DIM + w * 256 + lo;
  }

  const short* BpL = Bp + (size_t)(w * 256 + lo) * DP + hi * 8;
  #pragma unroll 4
  for (int nt = 0; nt < 16; ++nt) {
    f32x4 acc = (f32x4){0.f, 0.f, 0.f, 0.f};
    #pragma unroll
    for (int ks = 0; ks < KS2; ++ks) {
      short8v bf = *(const short8v*)(BpL + (size_t)nt * 16 * DP + ks * 32);
      acc = __builtin_amdgcn_mfma_f32_16x16x32_bf16(tf[ks], bf, acc, 0, 0, 0);
    }
    #pragma unroll
    for (int j = 0; j < 4; ++j)
      op[j][nt * 16] = acc[j] + lgvr[j];
  }
}

__global__ __launch_bounds__(256) void k_expert(const float* __restrict__ x,
                                                const short* __restrict__ A16,
                                                const short* __restrict__ B16,
                                                const int* __restrict__ list,
                                                const float* __restrict__ lg,
                                                const int* __restrict__ counts,
                                                float* __restrict__ out) {
  __shared__ __align__(16) char lds[21248];  // max: 2*16*132*4 + 16*136*2
  const int e = blockIdx.y;
  const int cnt = counts[e];
  if ((int)blockIdx.x * 16 >= cnt) return;
  switch (e) {
    case 0: expert_mfma<0>(x, A16, B16, list + 0 * NTOK, lg, cnt, out, lds); break;
    case 1: expert_mfma<1>(x, A16, B16, list + 1 * NTOK, lg, cnt, out, lds); break;
    case 2: expert_mfma<2>(x, A16, B16, list + 2 * NTOK, lg, cnt, out, lds); break;
    case 3: expert_mfma<3>(x, A16, B16, list + 3 * NTOK, lg, cnt, out, lds); break;
    case 4: expert_mfma<4>(x, A16, B16, list + 4 * NTOK, lg, cnt, out, lds); break;
    case 5: expert_mfma<5>(x, A16, B16, list + 5 * NTOK, lg, cnt, out, lds); break;
    case 6: expert_mfma<6>(x, A16, B16, list + 6 * NTOK, lg, cnt, out, lds); break;
  }
}

extern "C" void kernel_launch(void* const* d_in, const int* in_sizes, int n_in,
                              void* d_out, int out_size, void* d_ws, size_t ws_size,
                              hipStream_t stream) {
  const float* x     = (const float*)d_in[0];
  const float* proto = (const float*)d_in[1];
  ExpPtrs p;
  for (int e = 0; e < NE; ++e) {
    p.A[e] = (const float*)d_in[2 + 2 * e];
    p.B[e] = (const float*)d_in[3 + 2 * e];
  }
  float* wsf = (float*)d_ws;
  int*   wsi = (int*)d_ws;
  short* A16 = (short*)(wsf + A16_OFF);
  short* B16 = (short*)(wsf + B16_OFF);
  float* out = (float*)d_out;

  k_conv<<<dim3(16, NE), 256, 0, stream>>>(p, A16, B16, proto, wsf, wsi + CNT_OFF);
  k_sim<<<2048, 256, 0, stream>>>(x, wsf, wsf + E0_OFF, wsf + PR1_OFF);
  k_pass<1><<<128, 256, 0, stream>>>(wsf + E0_OFF, wsf, wsf + PR1_OFF, 2048,
                                     wsf + PR2_OFF, nullptr, nullptr, nullptr);
  k_pass<2><<<128, 256, 0, stream>>>(wsf + E0_OFF, wsf, wsf + PR2_OFF, 128,
                                     wsf + PR3_OFF, nullptr, nullptr, nullptr);
  k_pass<3><<<128, 256, 0, stream>>>(wsf + E0_OFF, wsf, wsf + PR3_OFF, 128,
                                     nullptr, wsi + CNT_OFF, wsi + LIST_OFF, wsf + LG_OFF);
  k_expert<<<dim3(2048, NE), 256, 0, stream>>>(x, A16, B16, wsi + LIST_OFF,
                                               wsf + LG_OFF, wsi + CNT_OFF, out);
}

// Round 4
// 194.988 us; speedup vs baseline: 5.2404x; 1.6657x over previous
//
#include <hip/hip_runtime.h>
#include <math.h>

#define NTOK 32768
#define DIM  1024
#define NE   7

// ws layout (4-byte units), ~3.94 MB
#define PN_OFF   0        // 7*1024 normalized prototypes (f32)
#define R1_OFF   7168
#define R2_OFF   7176
#define R3_OFF   7184
#define CNT_OFF  7192     // 8 ints
#define PR1_OFF  7200     // 2048*8
#define PR2_OFF  23584    // 128*8
#define PR3_OFF  24608    // 128*8
#define E0_OFF   25632    // NTOK*8 exp(sim/kappa)
#define LG_OFF   287776   // NTOK: log(top-1 gate)
#define LIST_OFF 320544   // NE*NTOK ints
#define A16_OFF  549920   // bf16 A weights (padded rows)
#define B16_OFF  754720   // bf16 B weights (padded cols)

#define SEPS 1e-6f

typedef __attribute__((ext_vector_type(8))) short short8v;
typedef __attribute__((ext_vector_type(4))) float f32x4;

// per-expert geometry
constexpr int DV[7]   = {8, 16, 32, 48, 64, 96, 128};
constexpr int DPV[7]  = {32, 32, 32, 64, 64, 96, 128};   // K-padded (mult 32)
constexpr int DAPV[7] = {16, 16, 32, 48, 64, 96, 128};   // N-padded (mult 16)
constexpr int AOV[7]  = {0, 16384, 32768, 65536, 114688, 180224, 278528};
constexpr int BOV[7]  = {0, 32768, 65536, 98304, 163840, 229376, 327680};

struct ExpPtrs { const float* A[NE]; const float* B[NE]; };

__device__ __forceinline__ short f2bf(float f) {
  union { float f; unsigned u; } v; v.f = f;
  return (short)((v.u + 0x7FFFu + ((v.u >> 16) & 1u)) >> 16);  // RNE
}

__device__ __forceinline__ float wsum(float v) {
  #pragma unroll
  for (int off = 32; off > 0; off >>= 1) v += __shfl_xor(v, off);
  return v;
}

__device__ __forceinline__ float dot4acc(float4 a, float4 b, float acc) {
  acc = fmaf(a.x, b.x, acc);
  acc = fmaf(a.y, b.y, acc);
  acc = fmaf(a.z, b.z, acc);
  acc = fmaf(a.w, b.w, acc);
  return acc;
}

__device__ __forceinline__ void ecfg(int e, int& d, int& dp, int& dap, int& ao, int& bo) {
  switch (e) {
    case 0: d = 8;   dp = 32;  dap = 16;  ao = 0;      bo = 0;      break;
    case 1: d = 16;  dp = 32;  dap = 16;  ao = 16384;  bo = 32768;  break;
    case 2: d = 32;  dp = 32;  dap = 32;  ao = 32768;  bo = 65536;  break;
    case 3: d = 48;  dp = 64;  dap = 48;  ao = 65536;  bo = 98304;  break;
    case 4: d = 64;  dp = 64;  dap = 64;  ao = 114688; bo = 163840; break;
    case 5: d = 96;  dp = 96;  dap = 96;  ao = 180224; bo = 229376; break;
    default: d = 128; dp = 128; dap = 128; ao = 278528; bo = 327680; break;
  }
}

// ---------------- K0: bf16 weight conversion + (block x==0) proto prep ----------------
__global__ __launch_bounds__(256) void k_conv(ExpPtrs p, short* __restrict__ A16,
                                              short* __restrict__ B16,
                                              const float* __restrict__ proto,
                                              float* __restrict__ wsf,
                                              int* __restrict__ counts) {
  const int e = blockIdx.y;
  const int tid = threadIdx.x;
  int d, dp, dap, ao, bo;
  ecfg(e, d, dp, dap, ao, bo);

  if (blockIdx.x == 0) {
    __shared__ float pred[4];
    if (e == 0 && tid < 8) counts[tid] = 0;
    const int w = tid >> 6, lane = tid & 63;
    float v4[4], ss = 0.f;
    #pragma unroll
    for (int i = 0; i < 4; ++i) {
      v4[i] = proto[e * DIM + tid + 256 * i];
      ss = fmaf(v4[i], v4[i], ss);
    }
    ss = wsum(ss);
    if (lane == 0) pred[w] = ss;
    __syncthreads();
    float tot = ((pred[0] + pred[1]) + pred[2]) + pred[3];
    float inv = 1.f / fmaxf(sqrtf(tot), 1e-12f);
    #pragma unroll
    for (int i = 0; i < 4; ++i)
      wsf[PN_OFF + e * DIM + tid + 256 * i] = v4[i] * inv;
  }

  const float* A = p.A[e];
  const float* B = p.B[e];
  short* Ad = A16 + ao;
  short* Bd = B16 + bo;
  const int t0 = blockIdx.x * 256 + tid;
  for (int i = t0; i < dap * DIM; i += 16 * 256) {
    int row = i >> 10;
    Ad[i] = (row < d) ? f2bf(A[i]) : (short)0;
  }
  for (int i = t0; i < DIM * dp; i += 16 * 256) {
    int j = i / dp, r = i - j * dp;
    Bd[i] = (r < d) ? f2bf(B[j * d + r]) : (short)0;
  }
}

// ---------------- K1: sim -> e0 = exp(sim/kappa), block partials of R1 ----------------
__global__ __launch_bounds__(256) void k_sim(const float* __restrict__ x,
                                             const float* __restrict__ wsf,
                                             float* __restrict__ e0,
                                             float* __restrict__ pr1) {
  const int tid = threadIdx.x, w = tid >> 6, lane = tid & 63;
  const float4* pn4 = (const float4*)(wsf + PN_OFF);
  const int gw = blockIdx.x * 4 + w;
  float r1a[NE] = {0.f, 0.f, 0.f, 0.f, 0.f, 0.f, 0.f};
  for (int it = 0; it < 4; ++it) {
    const int n = gw + 8192 * it;
    const float4* xr4 = (const float4*)(x + (size_t)n * DIM);
    float xx = 0.f;
    float dk[NE] = {0.f, 0.f, 0.f, 0.f, 0.f, 0.f, 0.f};
    #pragma unroll
    for (int i = 0; i < 4; ++i) {
      float4 xv = xr4[lane + 64 * i];
      xx = dot4acc(xv, xv, xx);
      #pragma unroll
      for (int k = 0; k < NE; ++k)
        dk[k] = dot4acc(xv, pn4[k * 256 + lane + 64 * i], dk[k]);
    }
    xx = wsum(xx);
    #pragma unroll
    for (int k = 0; k < NE; ++k) dk[k] = wsum(dk[k]);
    if (lane == 0) {
      float nrm = fmaxf(sqrtf(xx), 1e-12f);
      #pragma unroll
      for (int k = 0; k < NE; ++k) {
        float ev = expf((dk[k] / nrm) / 0.1f);
        e0[(size_t)n * 8 + k] = ev;
        r1a[k] += ev;
      }
    }
  }
  __shared__ float red[4][8];
  if (lane == 0) {
    #pragma unroll
    for (int k = 0; k < NE; ++k) red[w][k] = r1a[k];
  }
  __syncthreads();
  if (tid == 0) {
    #pragma unroll
    for (int k = 0; k < NE; ++k)
      pr1[blockIdx.x * 8 + k] = ((red[0][k] + red[1][k]) + red[2][k]) + red[3][k];
  }
}

#define SUM7(l) (((((((l)[0] + (l)[1]) + (l)[2]) + (l)[3]) + (l)[4]) + (l)[5]) + (l)[6])

// ---------------- sinkhorn passes; each self-reduces prior partials ----------------
template<int DEPTH>
__global__ __launch_bounds__(256) void k_pass(const float* __restrict__ e0,
                                              float* __restrict__ wsf,
                                              const float* __restrict__ src, int nb,
                                              float* __restrict__ prOut,
                                              int* __restrict__ counts,
                                              int* __restrict__ list,
                                              float* __restrict__ lgv) {
  __shared__ float red2[8][33];
  __shared__ float Rcur[8];
  const int tid = threadIdx.x;
  {
    const int k = tid & 7, m = tid >> 3;
    float a = 0.f;
    for (int b = m; b < nb; b += 32) a += src[b * 8 + k];
    red2[k][m] = a;
    __syncthreads();
    if (tid < 8) {
      float s = 0.f;
      for (int mm = 0; mm < 32; ++mm) s += red2[tid][mm];
      Rcur[tid] = s;
      if (blockIdx.x == 0) {
        int roff = (DEPTH == 1) ? R1_OFF : (DEPTH == 2) ? R2_OFF : R3_OFF;
        wsf[roff + tid] = s;
      }
    }
    __syncthreads();
  }

  const int n = blockIdx.x * 256 + tid;
  float4 v0 = *(const float4*)(e0 + (size_t)n * 8);
  float4 v1 = *(const float4*)(e0 + (size_t)n * 8 + 4);
  float l[NE] = {v0.x, v0.y, v0.z, v0.w, v1.x, v1.y, v1.z};
  {
    const float* R1 = (DEPTH == 1) ? Rcur : (wsf + R1_OFF);
    #pragma unroll
    for (int k = 0; k < NE; ++k) l[k] = l[k] / (R1[k] + SEPS);
    float C = SUM7(l);
    #pragma unroll
    for (int k = 0; k < NE; ++k) l[k] = l[k] / (C + SEPS);
  }
  if constexpr (DEPTH >= 2) {
    const float* R2 = (DEPTH == 2) ? Rcur : (wsf + R2_OFF);
    #pragma unroll
    for (int k = 0; k < NE; ++k) l[k] = l[k] / (R2[k] + SEPS);
    float C = SUM7(l);
    #pragma unroll
    for (int k = 0; k < NE; ++k) l[k] = l[k] / (C + SEPS);
  }
  if constexpr (DEPTH >= 3) {
    const float* R3 = Rcur;
    #pragma unroll
    for (int k = 0; k < NE; ++k) l[k] = l[k] / (R3[k] + SEPS);
    float C = SUM7(l);
    #pragma unroll
    for (int k = 0; k < NE; ++k) l[k] = l[k] / (C + SEPS);
  }
  if constexpr (DEPTH == 3) {
    float best = l[0]; int be = 0;
    #pragma unroll
    for (int k = 1; k < NE; ++k) {
      if (l[k] > best) { best = l[k]; be = k; }
    }
    // two-level slot reservation: wave ballot -> LDS counts -> 7 global atomics/block
    __shared__ int lcnt[8];
    __shared__ int wbase[4][8];
    __shared__ int gbase[8];
    const int w = tid >> 6, lane = tid & 63;
    if (tid < 8) lcnt[tid] = 0;
    __syncthreads();
    int rank = 0;
    #pragma unroll
    for (int k = 0; k < NE; ++k) {
      unsigned long long m = __ballot(be == k);
      if (lane == 0) wbase[w][k] = m ? atomicAdd(&lcnt[k], (int)__popcll(m)) : 0;
      if (be == k) rank = (int)__popcll(m & ((1ull << lane) - 1ull));
    }
    __syncthreads();
    if (tid < 8) gbase[tid] = lcnt[tid] ? atomicAdd(&counts[tid], lcnt[tid]) : 0;
    __syncthreads();
    int pos = gbase[be] + wbase[w][be] + rank;
    list[be * NTOK + pos] = n;
    lgv[n] = logf(best);
  } else {
    __shared__ float red[NE][256];
    #pragma unroll
    for (int k = 0; k < NE; ++k) red[k][tid] = l[k];
    __syncthreads();
    for (int off = 128; off > 0; off >>= 1) {
      if (tid < off) {
        #pragma unroll
        for (int k = 0; k < NE; ++k) red[k][tid] += red[k][tid + off];
      }
      __syncthreads();
    }
    if (tid < NE) prOut[blockIdx.x * 8 + tid] = red[tid][0];
  }
}

// ---------------- routed expert LoRA via bf16 MFMA, K-split + col-split ----------------
template<int E>
__device__ void expert_mfma(const float* __restrict__ x,
                            const short* __restrict__ A16,
                            const short* __restrict__ B16,
                            const int* __restrict__ list_e,
                            const float* __restrict__ lg,
                            int cnt, float* __restrict__ out,
                            char* lds) {
  constexpr int DP = DPV[E], DAP = DAPV[E];
  constexpr int NT1 = DAP / 16;   // phase-1 N-tiles
  constexpr int KS2 = DP / 32;    // phase-2 K-steps
  constexpr int PP  = DAP + 4;    // f32 partial pitch
  constexpr int SP  = DP + 8;     // bf16 T pitch
  float* P = (float*)lds;                         // [2][16][PP]
  short* T = (short*)(lds + 2 * 16 * PP * 4);     // [16][SP]

  const short* Am = A16 + AOV[E];
  const short* Bp = B16 + BOV[E];
  const int tid = threadIdx.x;
  const int w = tid >> 6, lane = tid & 63;
  const int lo = lane & 15, hi = lane >> 4;
  const int m0 = blockIdx.x * 16;

  // ---- phase 1: partial over K-chunk of 256 ----
  const int myTok = list_e[min(m0 + lo, cnt - 1)];
  const float* xp = x + (size_t)myTok * DIM + w * 256 + hi * 8;
  const short* ApL = Am + lo * DIM + w * 256 + hi * 8;

  f32x4 acc1[NT1];
  #pragma unroll
  for (int t = 0; t < NT1; ++t) acc1[t] = (f32x4){0.f, 0.f, 0.f, 0.f};

  float4 nx0 = *(const float4*)(xp);
  float4 nx1 = *(const float4*)(xp + 4);
  #pragma unroll
  for (int kc = 0; kc < 256; kc += 32) {
    float4 x0 = nx0, x1 = nx1;
    if (kc + 32 < 256) {
      nx0 = *(const float4*)(xp + kc + 32);
      nx1 = *(const float4*)(xp + kc + 36);
    }
    short8v af;
    af[0] = f2bf(x0.x); af[1] = f2bf(x0.y); af[2] = f2bf(x0.z); af[3] = f2bf(x0.w);
    af[4] = f2bf(x1.x); af[5] = f2bf(x1.y); af[6] = f2bf(x1.z); af[7] = f2bf(x1.w);
    #pragma unroll
    for (int t = 0; t < NT1; ++t) {
      short8v bf = *(const short8v*)(ApL + t * 16 * DIM + kc);
      acc1[t] = __builtin_amdgcn_mfma_f32_16x16x32_bf16(af, bf, acc1[t], 0, 0, 0);
    }
  }

  // ---- LDS reduce: waves 0,1 write; waves 2,3 add; combine -> bf16 T ----
  float* Pw = P + (w & 1) * 16 * PP;
  if (w < 2) {
    #pragma unroll
    for (int t = 0; t < NT1; ++t)
      #pragma unroll
      for (int j = 0; j < 4; ++j)
        Pw[(hi * 4 + j) * PP + t * 16 + lo] = acc1[t][j];
  }
  __syncthreads();
  if (w >= 2) {
    #pragma unroll
    for (int t = 0; t < NT1; ++t)
      #pragma unroll
      for (int j = 0; j < 4; ++j)
        Pw[(hi * 4 + j) * PP + t * 16 + lo] += acc1[t][j];
  }
  __syncthreads();
  for (int i = tid; i < 16 * DP; i += 256) {
    int r = i / DP, c = i - r * DP;
    float v = (c < DAP) ? (P[r * PP + c] + P[(16 + r) * PP + c]) : 0.f;
    T[r * SP + c] = f2bf(v);
  }
  __syncthreads();

  // ---- phase 2: cols [w*256, +256) ----
  short8v tf[KS2];
  #pragma unroll
  for (int ks = 0; ks < KS2; ++ks)
    tf[ks] = *(const short8v*)(T + lo * SP + ks * 32 + hi * 8);

  float  lgvr[4];
  float* op[4];
  #pragma unroll
  for (int j = 0; j < 4; ++j) {
    int t = list_e[min(m0 + hi * 4 + j, cnt - 1)];
    lgvr[j] = lg[t];
    op[j] = out + (size_t)t * DIM + w * 256 + lo;
  }

  const short* BpL = Bp + (size_t)(w * 256 + lo) * DP + hi * 8;
  #pragma unroll 4
  for (int nt = 0; nt < 16; ++nt) {
    f32x4 acc = (f32x4){0.f, 0.f, 0.f, 0.f};
    #pragma unroll
    for (int ks = 0; ks < KS2; ++ks) {
      short8v bf = *(const short8v*)(BpL + (size_t)nt * 16 * DP + ks * 32);
      acc = __builtin_amdgcn_mfma_f32_16x16x32_bf16(tf[ks], bf, acc, 0, 0, 0);
    }
    #pragma unroll
    for (int j = 0; j < 4; ++j)
      op[j][nt * 16] = acc[j] + lgvr[j];
  }
}

__global__ __launch_bounds__(256) void k_expert(const float* __restrict__ x,
                                                const short* __restrict__ A16,
                                                const short* __restrict__ B16,
                                                const int* __restrict__ list,
                                                const float* __restrict__ lg,
                                                const int* __restrict__ counts,
                                                float* __restrict__ out) {
  __shared__ __align__(16) char lds[21248];  // max: 2*16*132*4 + 16*136*2
  const int e = blockIdx.y;
  const int cnt = counts[e];
  if ((int)blockIdx.x * 16 >= cnt) return;
  switch (e) {
    case 0: expert_mfma<0>(x, A16, B16, list + 0 * NTOK, lg, cnt, out, lds); break;
    case 1: expert_mfma<1>(x, A16, B16, list + 1 * NTOK, lg, cnt, out, lds); break;
    case 2: expert_mfma<2>(x, A16, B16, list + 2 * NTOK, lg, cnt, out, lds); break;
    case 3: expert_mfma<3>(x, A16, B16, list + 3 * NTOK, lg, cnt, out, lds); break;
    case 4: expert_mfma<4>(x, A16, B16, list + 4 * NTOK, lg, cnt, out, lds); break;
    case 5: expert_mfma<5>(x, A16, B16, list + 5 * NTOK, lg, cnt, out, lds); break;
    case 6: expert_mfma<6>(x, A16, B16, list + 6 * NTOK, lg, cnt, out, lds); break;
  }
}

extern "C" void kernel_launch(void* const* d_in, const int* in_sizes, int n_in,
                              void* d_out, int out_size, void* d_ws, size_t ws_size,
                              hipStream_t stream) {
  const float* x     = (const float*)d_in[0];
  const float* proto = (const float*)d_in[1];
  ExpPtrs p;
  for (int e = 0; e < NE; ++e) {
    p.A[e] = (const float*)d_in[2 + 2 * e];
    p.B[e] = (const float*)d_in[3 + 2 * e];
  }
  float* wsf = (float*)d_ws;
  int*   wsi = (int*)d_ws;
  short* A16 = (short*)(wsf + A16_OFF);
  short* B16 = (short*)(wsf + B16_OFF);
  float* out = (float*)d_out;

  k_conv<<<dim3(16, NE), 256, 0, stream>>>(p, A16, B16, proto, wsf, wsi + CNT_OFF);
  k_sim<<<2048, 256, 0, stream>>>(x, wsf, wsf + E0_OFF, wsf + PR1_OFF);
  k_pass<1><<<128, 256, 0, stream>>>(wsf + E0_OFF, wsf, wsf + PR1_OFF, 2048,
                                     wsf + PR2_OFF, nullptr, nullptr, nullptr);
  k_pass<2><<<128, 256, 0, stream>>>(wsf + E0_OFF, wsf, wsf + PR2_OFF, 128,
                                     wsf + PR3_OFF, nullptr, nullptr, nullptr);
  k_pass<3><<<128, 256, 0, stream>>>(wsf + E0_OFF, wsf, wsf + PR3_OFF, 128,
                                     nullptr, wsi + CNT_OFF, wsi + LIST_OFF, wsf + LG_OFF);
  k_expert<<<dim3(2048, NE), 256, 0, stream>>>(x, A16, B16, wsi + LIST_OFF,
                                               wsf + LG_OFF, wsi + CNT_OFF, out);
}

// Round 5
// 192.941 us; speedup vs baseline: 5.2960x; 1.0106x over previous
//
#include <hip/hip_runtime.h>
#include <math.h>

#define NTOK 32768
#define DIM  1024
#define NE   7

// ws layout (4-byte units), ~3.94 MB
#define PN_OFF   0        // 7*1024 normalized prototypes (f32)
#define R1_OFF   7168
#define R2_OFF   7176
#define R3_OFF   7184
#define CNT_OFF  7192     // 8 ints
#define PR1_OFF  7200     // 2048*8
#define PR2_OFF  23584    // 128*8
#define PR3_OFF  24608    // 128*8
#define E0_OFF   25632    // NTOK*8 exp(sim/kappa)
#define LG_OFF   287776   // NTOK: log(top-1 gate)
#define LIST_OFF 320544   // NE*NTOK ints
#define A16_OFF  549920   // bf16 A weights (padded rows)
#define B16_OFF  754720   // bf16 B weights (padded cols)

#define SEPS 1e-6f

typedef __attribute__((ext_vector_type(8))) short short8v;
typedef __attribute__((ext_vector_type(4))) float f32x4;

// per-expert geometry
constexpr int DV[7]   = {8, 16, 32, 48, 64, 96, 128};
constexpr int DPV[7]  = {32, 32, 32, 64, 64, 96, 128};   // K-padded (mult 32)
constexpr int DAPV[7] = {16, 16, 32, 48, 64, 96, 128};   // N-padded (mult 16)
constexpr int AOV[7]  = {0, 16384, 32768, 65536, 114688, 180224, 278528};
constexpr int BOV[7]  = {0, 32768, 65536, 98304, 163840, 229376, 327680};

struct ExpPtrs { const float* A[NE]; const float* B[NE]; };

__device__ __forceinline__ short f2bf(float f) {
  union { float f; unsigned u; } v; v.f = f;
  return (short)((v.u + 0x7FFFu + ((v.u >> 16) & 1u)) >> 16);  // RNE
}

__device__ __forceinline__ float wsum(float v) {
  #pragma unroll
  for (int off = 32; off > 0; off >>= 1) v += __shfl_xor(v, off);
  return v;
}

__device__ __forceinline__ float dot4acc(float4 a, float4 b, float acc) {
  acc = fmaf(a.x, b.x, acc);
  acc = fmaf(a.y, b.y, acc);
  acc = fmaf(a.z, b.z, acc);
  acc = fmaf(a.w, b.w, acc);
  return acc;
}

__device__ __forceinline__ void ecfg(int e, int& d, int& dp, int& dap, int& ao, int& bo) {
  switch (e) {
    case 0: d = 8;   dp = 32;  dap = 16;  ao = 0;      bo = 0;      break;
    case 1: d = 16;  dp = 32;  dap = 16;  ao = 16384;  bo = 32768;  break;
    case 2: d = 32;  dp = 32;  dap = 32;  ao = 32768;  bo = 65536;  break;
    case 3: d = 48;  dp = 64;  dap = 48;  ao = 65536;  bo = 98304;  break;
    case 4: d = 64;  dp = 64;  dap = 64;  ao = 114688; bo = 163840; break;
    case 5: d = 96;  dp = 96;  dap = 96;  ao = 180224; bo = 229376; break;
    default: d = 128; dp = 128; dap = 128; ao = 278528; bo = 327680; break;
  }
}

// ---------------- K0: bf16 weight conversion + (block x==0) proto prep ----------------
__global__ __launch_bounds__(256) void k_conv(ExpPtrs p, short* __restrict__ A16,
                                              short* __restrict__ B16,
                                              const float* __restrict__ proto,
                                              float* __restrict__ wsf,
                                              int* __restrict__ counts) {
  const int e = blockIdx.y;
  const int tid = threadIdx.x;
  int d, dp, dap, ao, bo;
  ecfg(e, d, dp, dap, ao, bo);

  if (blockIdx.x == 0) {
    __shared__ float pred[4];
    if (e == 0 && tid < 8) counts[tid] = 0;
    const int w = tid >> 6, lane = tid & 63;
    float v4[4], ss = 0.f;
    #pragma unroll
    for (int i = 0; i < 4; ++i) {
      v4[i] = proto[e * DIM + tid + 256 * i];
      ss = fmaf(v4[i], v4[i], ss);
    }
    ss = wsum(ss);
    if (lane == 0) pred[w] = ss;
    __syncthreads();
    float tot = ((pred[0] + pred[1]) + pred[2]) + pred[3];
    float inv = 1.f / fmaxf(sqrtf(tot), 1e-12f);
    #pragma unroll
    for (int i = 0; i < 4; ++i)
      wsf[PN_OFF + e * DIM + tid + 256 * i] = v4[i] * inv;
  }

  const float* A = p.A[e];
  const float* B = p.B[e];
  short* Ad = A16 + ao;
  short* Bd = B16 + bo;
  const int t0 = blockIdx.x * 256 + tid;
  for (int i = t0; i < dap * DIM; i += 16 * 256) {
    int row = i >> 10;
    Ad[i] = (row < d) ? f2bf(A[i]) : (short)0;
  }
  for (int i = t0; i < DIM * dp; i += 16 * 256) {
    int j = i / dp, r = i - j * dp;
    Bd[i] = (r < d) ? f2bf(B[j * d + r]) : (short)0;
  }
}

// ---------------- K1: sim -> e0 = exp(sim/kappa), block partials of R1 ----------------
__global__ __launch_bounds__(256) void k_sim(const float* __restrict__ x,
                                             const float* __restrict__ wsf,
                                             float* __restrict__ e0,
                                             float* __restrict__ pr1) {
  const int tid = threadIdx.x, w = tid >> 6, lane = tid & 63;
  const float4* pn4 = (const float4*)(wsf + PN_OFF);
  const int gw = blockIdx.x * 4 + w;
  float r1a[NE] = {0.f, 0.f, 0.f, 0.f, 0.f, 0.f, 0.f};
  for (int it = 0; it < 4; ++it) {
    const int n = gw + 8192 * it;
    const float4* xr4 = (const float4*)(x + (size_t)n * DIM);
    float xx = 0.f;
    float dk[NE] = {0.f, 0.f, 0.f, 0.f, 0.f, 0.f, 0.f};
    #pragma unroll
    for (int i = 0; i < 4; ++i) {
      float4 xv = xr4[lane + 64 * i];
      xx = dot4acc(xv, xv, xx);
      #pragma unroll
      for (int k = 0; k < NE; ++k)
        dk[k] = dot4acc(xv, pn4[k * 256 + lane + 64 * i], dk[k]);
    }
    xx = wsum(xx);
    #pragma unroll
    for (int k = 0; k < NE; ++k) dk[k] = wsum(dk[k]);
    if (lane == 0) {
      float nrm = fmaxf(sqrtf(xx), 1e-12f);
      #pragma unroll
      for (int k = 0; k < NE; ++k) {
        float ev = expf((dk[k] / nrm) / 0.1f);
        e0[(size_t)n * 8 + k] = ev;
        r1a[k] += ev;
      }
    }
  }
  __shared__ float red[4][8];
  if (lane == 0) {
    #pragma unroll
    for (int k = 0; k < NE; ++k) red[w][k] = r1a[k];
  }
  __syncthreads();
  if (tid == 0) {
    #pragma unroll
    for (int k = 0; k < NE; ++k)
      pr1[blockIdx.x * 8 + k] = ((red[0][k] + red[1][k]) + red[2][k]) + red[3][k];
  }
}

#define SUM7(l) (((((((l)[0] + (l)[1]) + (l)[2]) + (l)[3]) + (l)[4]) + (l)[5]) + (l)[6])

// ---------------- sinkhorn passes; each self-reduces prior partials ----------------
template<int DEPTH>
__global__ __launch_bounds__(256) void k_pass(const float* __restrict__ e0,
                                              float* __restrict__ wsf,
                                              const float* __restrict__ src, int nb,
                                              float* __restrict__ prOut,
                                              int* __restrict__ counts,
                                              int* __restrict__ list,
                                              float* __restrict__ lgv) {
  __shared__ float red2[8][33];
  __shared__ float Rcur[8];
  const int tid = threadIdx.x;
  {
    const int k = tid & 7, m = tid >> 3;
    float a = 0.f;
    for (int b = m; b < nb; b += 32) a += src[b * 8 + k];
    red2[k][m] = a;
    __syncthreads();
    if (tid < 8) {
      float s = 0.f;
      for (int mm = 0; mm < 32; ++mm) s += red2[tid][mm];
      Rcur[tid] = s;
      if (blockIdx.x == 0) {
        int roff = (DEPTH == 1) ? R1_OFF : (DEPTH == 2) ? R2_OFF : R3_OFF;
        wsf[roff + tid] = s;
      }
    }
    __syncthreads();
  }

  const int n = blockIdx.x * 256 + tid;
  float4 v0 = *(const float4*)(e0 + (size_t)n * 8);
  float4 v1 = *(const float4*)(e0 + (size_t)n * 8 + 4);
  float l[NE] = {v0.x, v0.y, v0.z, v0.w, v1.x, v1.y, v1.z};
  {
    const float* R1 = (DEPTH == 1) ? Rcur : (wsf + R1_OFF);
    #pragma unroll
    for (int k = 0; k < NE; ++k) l[k] = l[k] / (R1[k] + SEPS);
    float C = SUM7(l);
    #pragma unroll
    for (int k = 0; k < NE; ++k) l[k] = l[k] / (C + SEPS);
  }
  if constexpr (DEPTH >= 2) {
    const float* R2 = (DEPTH == 2) ? Rcur : (wsf + R2_OFF);
    #pragma unroll
    for (int k = 0; k < NE; ++k) l[k] = l[k] / (R2[k] + SEPS);
    float C = SUM7(l);
    #pragma unroll
    for (int k = 0; k < NE; ++k) l[k] = l[k] / (C + SEPS);
  }
  if constexpr (DEPTH >= 3) {
    const float* R3 = Rcur;
    #pragma unroll
    for (int k = 0; k < NE; ++k) l[k] = l[k] / (R3[k] + SEPS);
    float C = SUM7(l);
    #pragma unroll
    for (int k = 0; k < NE; ++k) l[k] = l[k] / (C + SEPS);
  }
  if constexpr (DEPTH == 3) {
    float best = l[0]; int be = 0;
    #pragma unroll
    for (int k = 1; k < NE; ++k) {
      if (l[k] > best) { best = l[k]; be = k; }
    }
    // two-level slot reservation: wave ballot -> LDS counts -> 7 global atomics/block
    __shared__ int lcnt[8];
    __shared__ int wbase[4][8];
    __shared__ int gbase[8];
    const int w = tid >> 6, lane = tid & 63;
    if (tid < 8) lcnt[tid] = 0;
    __syncthreads();
    int rank = 0;
    #pragma unroll
    for (int k = 0; k < NE; ++k) {
      unsigned long long m = __ballot(be == k);
      if (lane == 0) wbase[w][k] = m ? atomicAdd(&lcnt[k], (int)__popcll(m)) : 0;
      if (be == k) rank = (int)__popcll(m & ((1ull << lane) - 1ull));
    }
    __syncthreads();
    if (tid < 8) gbase[tid] = lcnt[tid] ? atomicAdd(&counts[tid], lcnt[tid]) : 0;
    __syncthreads();
    int pos = gbase[be] + wbase[w][be] + rank;
    list[be * NTOK + pos] = n;
    lgv[n] = logf(best);
  } else {
    __shared__ float red[NE][256];
    #pragma unroll
    for (int k = 0; k < NE; ++k) red[k][tid] = l[k];
    __syncthreads();
    for (int off = 128; off > 0; off >>= 1) {
      if (tid < off) {
        #pragma unroll
        for (int k = 0; k < NE; ++k) red[k][tid] += red[k][tid + off];
      }
      __syncthreads();
    }
    if (tid < NE) prOut[blockIdx.x * 8 + tid] = red[tid][0];
  }
}

// ---------------- routed expert LoRA via bf16 MFMA, K-split + col-split ----------------
// Block = 16 tokens, 4 waves. Flattened 1-D grid: block derives (expert, tile)
// from on-the-fly prefix over counts (uniform scalar loop).
// Phase 1: wave w: partial T over K-chunk [w*256, +256); f32 partials in LDS (2 regions),
//          combine via registers, bf16 T overlays the partial region (saves 4.3 KB LDS).
// Phase 2: wave w: output cols [w*256, +256); out = y + log(g).
template<int E>
__device__ void expert_mfma(const float* __restrict__ x,
                            const short* __restrict__ A16,
                            const short* __restrict__ B16,
                            const int* __restrict__ list_e,
                            const float* __restrict__ lg,
                            int cnt, int tile, float* __restrict__ out,
                            char* lds) {
  constexpr int DP = DPV[E], DAP = DAPV[E];
  constexpr int NT1 = DAP / 16;   // phase-1 N-tiles
  constexpr int KS2 = DP / 32;    // phase-2 K-steps
  constexpr int PP  = DAP + 4;    // f32 partial pitch
  constexpr int SP  = DP + 8;     // bf16 T pitch
  float* P = (float*)lds;         // [2][16][PP]
  short* T = (short*)lds;         // [16][SP] — overlays P after reg-staged combine

  const short* Am = A16 + AOV[E];
  const short* Bp = B16 + BOV[E];
  const int tid = threadIdx.x;
  const int w = tid >> 6, lane = tid & 63;
  const int lo = lane & 15, hi = lane >> 4;
  const int m0 = tile * 16;

  // ---- phase 1: partial over K-chunk of 256 ----
  const int myTok = list_e[min(m0 + lo, cnt - 1)];
  const float* xp = x + (size_t)myTok * DIM + w * 256 + hi * 8;
  const short* ApL = Am + lo * DIM + w * 256 + hi * 8;

  f32x4 acc1[NT1];
  #pragma unroll
  for (int t = 0; t < NT1; ++t) acc1[t] = (f32x4){0.f, 0.f, 0.f, 0.f};

  float4 nx0 = *(const float4*)(xp);
  float4 nx1 = *(const float4*)(xp + 4);
  #pragma unroll
  for (int kc = 0; kc < 256; kc += 32) {
    float4 x0 = nx0, x1 = nx1;
    if (kc + 32 < 256) {
      nx0 = *(const float4*)(xp + kc + 32);
      nx1 = *(const float4*)(xp + kc + 36);
    }
    short8v af;
    af[0] = f2bf(x0.x); af[1] = f2bf(x0.y); af[2] = f2bf(x0.z); af[3] = f2bf(x0.w);
    af[4] = f2bf(x1.x); af[5] = f2bf(x1.y); af[6] = f2bf(x1.z); af[7] = f2bf(x1.w);
    #pragma unroll
    for (int t = 0; t < NT1; ++t) {
      short8v bf = *(const short8v*)(ApL + t * 16 * DIM + kc);
      acc1[t] = __builtin_amdgcn_mfma_f32_16x16x32_bf16(af, bf, acc1[t], 0, 0, 0);
    }
  }

  // ---- LDS reduce: waves 0,1 write; waves 2,3 add ----
  float* Pw = P + (w & 1) * 16 * PP;
  if (w < 2) {
    #pragma unroll
    for (int t = 0; t < NT1; ++t)
      #pragma unroll
      for (int j = 0; j < 4; ++j)
        Pw[(hi * 4 + j) * PP + t * 16 + lo] = acc1[t][j];
  }
  __syncthreads();
  if (w >= 2) {
    #pragma unroll
    for (int t = 0; t < NT1; ++t)
      #pragma unroll
      for (int j = 0; j < 4; ++j)
        Pw[(hi * 4 + j) * PP + t * 16 + lo] += acc1[t][j];
  }
  __syncthreads();
  // combine -> regs -> barrier -> bf16 T (overlaying P)
  constexpr int NITEM = (16 * DP + 255) / 256;
  float vloc[NITEM];
  #pragma unroll
  for (int it = 0; it < NITEM; ++it) {
    int i = tid + it * 256;
    float v = 0.f;
    if (i < 16 * DP) {
      int r = i / DP, c = i - r * DP;
      if (c < DAP) v = P[r * PP + c] + P[(16 + r) * PP + c];
    }
    vloc[it] = v;
  }
  __syncthreads();
  #pragma unroll
  for (int it = 0; it < NITEM; ++it) {
    int i = tid + it * 256;
    if (i < 16 * DP) {
      int r = i / DP, c = i - r * DP;
      T[r * SP + c] = f2bf(vloc[it]);
    }
  }
  __syncthreads();

  // ---- phase 2: cols [w*256, +256) ----
  short8v tf[KS2];
  #pragma unroll
  for (int ks = 0; ks < KS2; ++ks)
    tf[ks] = *(const short8v*)(T + lo * SP + ks * 32 + hi * 8);

  float  lgvr[4];
  float* op[4];
  #pragma unroll
  for (int j = 0; j < 4; ++j) {
    int t = list_e[min(m0 + hi * 4 + j, cnt - 1)];
    lgvr[j] = lg[t];
    op[j] = out + (size_t)t * DIM + w * 256 + lo;
  }

  const short* BpL = Bp + (size_t)(w * 256 + lo) * DP + hi * 8;
  #pragma unroll 4
  for (int nt = 0; nt < 16; ++nt) {
    f32x4 acc = (f32x4){0.f, 0.f, 0.f, 0.f};
    #pragma unroll
    for (int ks = 0; ks < KS2; ++ks) {
      short8v bf = *(const short8v*)(BpL + (size_t)nt * 16 * DP + ks * 32);
      acc = __builtin_amdgcn_mfma_f32_16x16x32_bf16(tf[ks], bf, acc, 0, 0, 0);
    }
    #pragma unroll
    for (int j = 0; j < 4; ++j)
      op[j][nt * 16] = acc[j] + lgvr[j];
  }
}

__global__ __launch_bounds__(256) void k_expert(const float* __restrict__ x,
                                                const short* __restrict__ A16,
                                                const short* __restrict__ B16,
                                                const int* __restrict__ list,
                                                const float* __restrict__ lg,
                                                const int* __restrict__ counts,
                                                float* __restrict__ out) {
  __shared__ __align__(16) char lds[16896];  // 2*16*(128+4)*4
  // flattened grid: find (expert, tile) via prefix over ceil(counts[e]/16)
  int rem = blockIdx.x;
  int e = 0, cnt;
  while (true) {
    cnt = counts[e];
    int tiles = (cnt + 15) >> 4;
    if (rem < tiles) break;
    rem -= tiles;
    if (++e == NE) return;
  }
  switch (e) {
    case 0: expert_mfma<0>(x, A16, B16, list + 0 * NTOK, lg, cnt, rem, out, lds); break;
    case 1: expert_mfma<1>(x, A16, B16, list + 1 * NTOK, lg, cnt, rem, out, lds); break;
    case 2: expert_mfma<2>(x, A16, B16, list + 2 * NTOK, lg, cnt, rem, out, lds); break;
    case 3: expert_mfma<3>(x, A16, B16, list + 3 * NTOK, lg, cnt, rem, out, lds); break;
    case 4: expert_mfma<4>(x, A16, B16, list + 4 * NTOK, lg, cnt, rem, out, lds); break;
    case 5: expert_mfma<5>(x, A16, B16, list + 5 * NTOK, lg, cnt, rem, out, lds); break;
    case 6: expert_mfma<6>(x, A16, B16, list + 6 * NTOK, lg, cnt, rem, out, lds); break;
  }
}

extern "C" void kernel_launch(void* const* d_in, const int* in_sizes, int n_in,
                              void* d_out, int out_size, void* d_ws, size_t ws_size,
                              hipStream_t stream) {
  const float* x     = (const float*)d_in[0];
  const float* proto = (const float*)d_in[1];
  ExpPtrs p;
  for (int e = 0; e < NE; ++e) {
    p.A[e] = (const float*)d_in[2 + 2 * e];
    p.B[e] = (const float*)d_in[3 + 2 * e];
  }
  float* wsf = (float*)d_ws;
  int*   wsi = (int*)d_ws;
  short* A16 = (short*)(wsf + A16_OFF);
  short* B16 = (short*)(wsf + B16_OFF);
  float* out = (float*)d_out;

  k_conv<<<dim3(16, NE), 256, 0, stream>>>(p, A16, B16, proto, wsf, wsi + CNT_OFF);
  k_sim<<<2048, 256, 0, stream>>>(x, wsf, wsf + E0_OFF, wsf + PR1_OFF);
  k_pass<1><<<128, 256, 0, stream>>>(wsf + E0_OFF, wsf, wsf + PR1_OFF, 2048,
                                     wsf + PR2_OFF, nullptr, nullptr, nullptr);
  k_pass<2><<<128, 256, 0, stream>>>(wsf + E0_OFF, wsf, wsf + PR2_OFF, 128,
                                     wsf + PR3_OFF, nullptr, nullptr, nullptr);
  k_pass<3><<<128, 256, 0, stream>>>(wsf + E0_OFF, wsf, wsf + PR3_OFF, 128,
                                     nullptr, wsi + CNT_OFF, wsi + LIST_OFF, wsf + LG_OFF);
  // flattened 1-D grid: max total tiles = 2048 + 6 (ceil rounding) -> 2055 covers all
  k_expert<<<2055, 256, 0, stream>>>(x, A16, B16, wsi + LIST_OFF,
                                     wsf + LG_OFF, wsi + CNT_OFF, out);
}